// Round 3
// baseline (1108.488 us; speedup 1.0000x reference)
//
#include <hip/hip_runtime.h>
#include <hip/hip_bf16.h>

#define B_ 16
#define S_ 2048
#define D_ 512
#define M_ (B_ * S_)  // 32768 rows for the GEMMs

typedef __attribute__((ext_vector_type(8))) _Float16 f16x8;
typedef __attribute__((ext_vector_type(4))) float f32x4;

// Async global->LDS direct copy, 16B per lane. LDS dest must be
// wave-uniform base + lane*16 (our staging layouts satisfy this: tid*16B).
#define GLOAD_LDS16(gp, lp)                                                   \
    __builtin_amdgcn_global_load_lds(                                         \
        (const __attribute__((address_space(1))) unsigned int*)(gp),          \
        (__attribute__((address_space(3))) unsigned int*)(lp), 16, 0, 0)

// ---------------------------------------------------------------------------
// Weight prep: cast fp32 W[l][h][512][1024] -> fp16 Wt[mat][1024][512]
// (transposed so B-operand fragments are contiguous 16B runs in k).
// 32x32 LDS transpose tiles, both global sides coalesced (R3).
// fp16 (not bf16): bf16 GEMM rounding amplified via sigmoid-gate * large-x
// gave absmax 4.5 > 1.68 (R1); fp16 cuts input rounding 8x -> 0.64 (R2).
// ---------------------------------------------------------------------------
__global__ __launch_bounds__(256) void prep_w_kernel(
    const float* __restrict__ fwW, const float* __restrict__ bwW,
    _Float16* __restrict__ Wt)
{
    __shared__ float tile[32][33];
    int bid = blockIdx.x;            // 8 mats * 16 k-tiles * 32 n-tiles = 4096
    int mat = bid >> 9;
    int t   = bid & 511;
    int kt  = t >> 5;                // 0..15  (k-tile)
    int nt  = t & 31;                // 0..31  (n-tile)
    int l   = mat >> 2;
    int dir = (mat >> 1) & 1;
    int h   = mat & 1;
    const float* src = (dir ? bwW : fwW) + (long long)(l * 2 + h) * (512LL * 1024);

    int tx = threadIdx.x & 31;       // fast dim (coalesced)
    int ty = threadIdx.x >> 5;       // 0..7
#pragma unroll
    for (int j = 0; j < 4; ++j) {
        int k = kt * 32 + ty + j * 8;
        tile[ty + j * 8][tx] = src[(long long)k * 1024 + nt * 32 + tx];
    }
    __syncthreads();
    _Float16* dst = Wt + (long long)mat * (1024LL * 512);
#pragma unroll
    for (int j = 0; j < 4; ++j) {
        int n = nt * 32 + ty + j * 8;
        dst[(long long)n * 512 + kt * 32 + tx] = (_Float16)tile[tx][ty + j * 8];
    }
}

// ---------------------------------------------------------------------------
// Band conv along S (unchanged; ~at BW roofline for its size).
// ---------------------------------------------------------------------------
__global__ __launch_bounds__(256) void band_conv_kernel(
    const float* __restrict__ src, long long bstride, int rstride,
    const float* __restrict__ w17, int causal,
    _Float16* __restrict__ Th)
{
    int id = blockIdx.x * 256 + threadIdx.x;  // B * (S/4) * D threads
    int c  = id & (D_ - 1);
    int tt = (id >> 9) & (S_ / 4 - 1);
    int b  = id >> 18;
    int t0 = tt * 4;

    float w[17];
#pragma unroll
    for (int e = 0; e < 17; ++e) w[e] = w17[e];

    float buf[20];
    int tbase = t0 - (causal ? 16 : 0);
    const float* sp = src + (long long)b * bstride + c;
#pragma unroll
    for (int i = 0; i < 20; ++i) {
        int t = tbase + i;
        buf[i] = (t >= 0 && t < S_) ? sp[(long long)t * rstride] : 0.f;
    }
#pragma unroll
    for (int j = 0; j < 4; ++j) {
        float a = 0.f;
#pragma unroll
        for (int e = 0; e <= 16; ++e) a = fmaf(w[e], buf[j + e], a);
        Th[((long long)(b * S_ + t0 + j)) * D_ + c] = (_Float16)a;
    }
}

// ---------------------------------------------------------------------------
// One highway iteration, fused: proj = X(fp16) @ W(fp16) + b, then
// out = sigmoid(gate)*x + (1-sigmoid(gate))*relu(nonlinear).
//
// R5 (on top of R4's counted-vmcnt 4-phase pipeline):
//  * sched_barrier(0) pins around every phase segment. s_barrier does NOT
//    stop LLVM reordering memory ops across it; without pins the stage
//    issues / next-phase ds_reads migrate and the interleave collapses
//    (m232-class null; m196: broken interleave costs 7-27%). The pin before
//    the trailing barrier also bounds cross-phase ds_read hoisting above
//    the vmcnt(2) (correctness of the counted schedule).
//  * Grid 256 = exactly one block/CU round. Each block runs a CONTINUOUS
//    16-tile pipeline over TWO 256-row panels (T>=8 -> panel 1); staging
//    never drains at the panel boundary. Panel-0 epilogue (no LDS: x read
//    direct from Xh, L2-hot) runs while panel-1 prefetches are in flight.
//  * Epilogue x-LDS-restage dropped (enables the no-LDS mid-loop epilogue;
//    also removes 8-way ds_read_u16 bank conflicts it had).
//
// Geometry: per block 2 x (256 rows x 128 out cols); BK=64; 512 thr = 8
// waves (4M x 2N); LDS 128KB = A[2buf][256][64] + B[2buf][256][64] fp16,
// B local rows 0-127 = nonlinear cols, 128-255 = gate cols. 1 block/CU.
//
// Per tile T (virtual kt = T&7, panel = T>>3): 4 phases (h=p&1, ks=p>>1):
//   {ds_read frags; stage one half-tile; [p3: vmcnt(2)]; SB0; s_barrier;
//    lgkmcnt(0); SB0; setprio(1); 16 MFMA; setprio(0); SB0; s_barrier}
// Stage schedule: p0 Alo(T+1), p1 Ahi(T+1), p2 Bhi(T+1) -> buf^1;
//                 p3 Blo(T+2) -> buf. vmcnt(2) at p3 => T+1's halves landed,
//                 Blo(T+2) stays in flight ACROSS barriers (T4: never drain
//                 to 0 in the main loop; T==14 drains as pipeline epilogue).
//
// MFMA 16x16x32 f16; verified layouts (dtype-independent on gfx950):
//   A frag: A[m=lane&15][k=q*8+j]; B frag: B[k=q*8+j][n=lane&15]
//   C/D:    row(m)=q*4+reg, col(n)=lane&15
// T2 swizzle: LDS byte = row*128 + (colbyte ^ ((row&7)<<4)); pre-permuted
// global source keeps the global_load_lds dest linear (rule 21).
// K-accumulation order identical to R3/R4 -> absmax stays 0.71875.
// ---------------------------------------------------------------------------
__global__ __launch_bounds__(512, 2) void hw_step_kernel(
    const _Float16* __restrict__ Xh,         // [M][512] fp16 GEMM + x input
    const _Float16* __restrict__ Wt,         // [1024][512] fp16 (k-contig)
    const float* __restrict__ bias,          // [1024]
    float* __restrict__ outF, int outF_stride,  // may be null
    _Float16* __restrict__ outH)                // may be null
{
    __shared__ _Float16 lds[65536];   // 128KB: A at byte 0, B at byte 65536
    char* ldsb = (char*)lds;

    int tid = threadIdx.x;

    // XCD-chunked swizzle: 256 blocks, 32/XCD, col-block fastest within the
    // chunk -> 4 col-blocks sharing an A row-panel co-reside on one XCD L2.
    int f = blockIdx.x;
    int L = (f & 7) * 32 + (f >> 3);  // 0..255
    int colb = L & 3;                 // 0..3
    int rp   = L >> 2;                // 0..63 -> two 256-row panels each
    long long m0 = (long long)rp * 512;
    int n0 = colb * 128;              // output-column base (0..511 space)

    int lane = tid & 63;
    int wave = tid >> 6;
    int wave_m = wave >> 1;           // 0..3 -> 64 rows each
    int wave_n = wave & 1;            // 0..1 -> 64 out cols each
    int wrow = wave_m * 64;
    int wn   = wave_n * 64;
    int ln = lane & 15;
    int q  = lane >> 4;

    // staging constants: thread t stages LDS slot (j*512+t)*16 of a 16KB
    // half-tile (128 rows x 128B). Local row = j*64 + (t>>3); source column
    // pre-permuted so the linear LDS write realizes the XOR-swizzle:
    // col_fp16 = kt*64 + 8*((t&7) ^ (row&7)).
    int rloc  = tid >> 3;                         // 0..63
    int cperm = 8 * ((tid & 7) ^ (rloc & 7));     // fp16 units, 16B-aligned
    const _Float16* gA  = Xh + (m0 + rloc) * 512 + cperm;
    const _Float16* gBn = Wt + (long long)(n0 + rloc) * 512 + cperm;
    const _Float16* gBg = Wt + (long long)(512 + n0 + rloc) * 512 + cperm;

    // half-tile stage by virtual tile index T1: A uses panel = T1>>3,
    // k-tile = T1&7; B repeats every 8 tiles (k-tile only).
    auto stageA = [&](int b, int T1, int h2) {
        long long roff =
            (long long)((T1 >> 3) * 256 + h2 * 128) * 512 + (T1 & 7) * 64;
#pragma unroll
        for (int j = 0; j < 2; ++j)
            GLOAD_LDS16(gA + roff + (long long)(j * 64) * 512,
                        ldsb + b * 32768 + h2 * 16384 + (j * 512 + tid) * 16);
    };
    auto stageB = [&](int b, int T1, int h2) {
        const _Float16* g = h2 ? gBg : gBn;
#pragma unroll
        for (int j = 0; j < 2; ++j)
            GLOAD_LDS16(g + (long long)(j * 64) * 512 + (T1 & 7) * 64,
                        ldsb + 65536 + b * 32768 + h2 * 16384 + (j * 512 + tid) * 16);
    };

    f32x4 acc[2][4][4];   // [h][jn][i]
#pragma unroll
    for (int h = 0; h < 2; ++h)
#pragma unroll
        for (int jn = 0; jn < 4; ++jn)
#pragma unroll
            for (int i = 0; i < 4; ++i) acc[h][jn][i] = (f32x4){0.f, 0.f, 0.f, 0.f};

    // Highway epilogue for one panel: registers + global only (NO LDS), so
    // it can run mid-pipeline with panel-1 prefetches still in flight.
    auto epilogue = [&](int pnl) {
        long long mb = m0 + pnl * 256;
#pragma unroll
        for (int jn = 0; jn < 4; ++jn) {
            int c = n0 + wn + jn * 16 + ln;   // 0..511
            float bnl = bias[c];
            float bg  = bias[512 + c];
#pragma unroll
            for (int i = 0; i < 4; ++i) {
#pragma unroll
                for (int r = 0; r < 4; ++r) {
                    long long m = mb + wrow + i * 16 + q * 4 + r;
                    float nl = acc[0][jn][i][r] + bnl;
                    float gt = acc[1][jn][i][r] + bg;
                    float g  = 1.f / (1.f + __expf(-gt));
                    float xv = (float)Xh[m * 512 + c];
                    float o  = g * xv + (1.f - g) * fmaxf(nl, 0.f);
                    if (outF) outF[m * (long long)outF_stride + c] = o;
                    if (outH) outH[m * 512 + c] = (_Float16)o;
                }
            }
        }
    };

    // ---- prologue: tile0 complete + Blo(1); vmcnt(2) leaves Blo(1) in flight
    stageB(0, 0, 0);
    stageA(0, 0, 0);
    stageA(0, 0, 1);
    stageB(0, 0, 1);
    stageB(1, 1, 0);
    asm volatile("s_waitcnt vmcnt(2)" ::: "memory");
    __builtin_amdgcn_s_barrier();

    f16x8 af[4];
    for (int T = 0; T < 16; ++T) {
        int b = T & 1;
        const char* Ab = ldsb + b * 32768;
        const char* Bb = ldsb + 65536 + b * 32768;
#pragma unroll
        for (int p = 0; p < 4; ++p) {
            const int h = p & 1, ks = p >> 1;
            const int cb = ks * 64 + q * 16;   // colbyte before swizzle
            // ds_read register subtiles (A reused across the two h-phases)
            if ((p & 1) == 0) {
#pragma unroll
                for (int i = 0; i < 4; ++i) {
                    int row = wrow + i * 16 + ln;
                    af[i] = *(const f16x8*)(Ab + row * 128 + (cb ^ ((row & 7) << 4)));
                }
            }
            f16x8 bf[4];
#pragma unroll
            for (int jn = 0; jn < 4; ++jn) {
                int row = h * 128 + wn + jn * 16 + ln;
                bf[jn] = *(const f16x8*)(Bb + row * 128 + (cb ^ ((row & 7) << 4)));
            }
            // stage (counted-vmcnt pipeline; see schedule above)
            if (p == 0) { if (T + 1 < 16) stageA(b ^ 1, T + 1, 0); }
            if (p == 1) { if (T + 1 < 16) stageA(b ^ 1, T + 1, 1); }
            if (p == 2) { if (T + 1 < 16) stageB(b ^ 1, T + 1, 1); }
            if (p == 3) {
                if (T + 2 < 16) stageB(b, T + 2, 0);
                if (T < 14)       asm volatile("s_waitcnt vmcnt(2)" ::: "memory");
                else if (T == 14) asm volatile("s_waitcnt vmcnt(0)" ::: "memory");
            }
            __builtin_amdgcn_sched_barrier(0);   // pin ds_reads+stages above
            __builtin_amdgcn_s_barrier();
            asm volatile("s_waitcnt lgkmcnt(0)" ::: "memory");
            __builtin_amdgcn_sched_barrier(0);   // rule 18: MFMA must not hoist
            __builtin_amdgcn_s_setprio(1);
#pragma unroll
            for (int jn = 0; jn < 4; ++jn)
#pragma unroll
                for (int i = 0; i < 4; ++i)
                    acc[h][jn][i] = __builtin_amdgcn_mfma_f32_16x16x32_f16(
                        af[i], bf[jn], acc[h][jn][i], 0, 0, 0);
            __builtin_amdgcn_s_setprio(0);
            __builtin_amdgcn_sched_barrier(0);   // pin MFMA above trailing bar
            __builtin_amdgcn_s_barrier();
        }
        if (T == 7) {
            // Panel-0 drain: no LDS use, panel-1 prefetches stay in flight.
            epilogue(0);
#pragma unroll
            for (int h = 0; h < 2; ++h)
#pragma unroll
                for (int jn = 0; jn < 4; ++jn)
#pragma unroll
                    for (int i = 0; i < 4; ++i)
                        acc[h][jn][i] = (f32x4){0.f, 0.f, 0.f, 0.f};
        }
    }
    epilogue(1);
}

// ---------------------------------------------------------------------------
extern "C" void kernel_launch(void* const* d_in, const int* in_sizes, int n_in,
                              void* d_out, int out_size, void* d_ws, size_t ws_size,
                              hipStream_t stream)
{
    const float* inputs  = (const float*)d_in[0];
    // d_in[1] = masks: all ones, unused by the reference
    const float* fw_band = (const float*)d_in[2];
    const float* bw_band = (const float*)d_in[3];
    const float* fw_W    = (const float*)d_in[4];
    const float* fw_b    = (const float*)d_in[5];
    const float* bw_W    = (const float*)d_in[6];
    const float* bw_b    = (const float*)d_in[7];
    float* out = (float*)d_out;  // [2][16][2048][1024]

    char* ws = (char*)d_ws;
    const size_t SZ_TH = (size_t)M_ * D_ * 2;    // 32 MB fp16 activation
    _Float16* Th = (_Float16*)(ws);
    _Float16* Hh = (_Float16*)(ws + SZ_TH);
    _Float16* Wt = (_Float16*)(ws + 2 * SZ_TH);  // 8 MB fp16 weights

    prep_w_kernel<<<4096, 256, 0, stream>>>(fw_W, bw_W, Wt);

    for (int l = 0; l < 2; ++l) {
        for (int dir = 0; dir < 2; ++dir) {
            const float* src; long long bstride; int rstride;
            if (l == 0) { src = inputs; bstride = (long long)S_ * D_; rstride = D_; }
            else {
                src = out + (long long)(l - 1) * M_ * 1024 + dir * 512;
                bstride = (long long)S_ * 1024; rstride = 1024;
            }
            const float* band = (dir ? bw_band : fw_band) + l * 17;
            band_conv_kernel<<<(B_ * (S_ / 4) * D_) / 256, 256, 0, stream>>>(
                src, bstride, rstride, band, dir == 0 ? 1 : 0, Th);

            const _Float16* W0 = Wt + (size_t)((l * 2 + dir) * 2 + 0) * (1024 * 512);
            const _Float16* W1 = Wt + (size_t)((l * 2 + dir) * 2 + 1) * (1024 * 512);
            const float* bias = (dir ? bw_b : fw_b) + (size_t)(l * 2) * 1024;

            // highway iter 0: Th -> Hh
            hw_step_kernel<<<256, 512, 0, stream>>>(Th, W0, bias, nullptr, 0, Hh);
            // highway iter 1: Hh -> d_out slice (fp32, stride 1024)
            float* oF = out + (long long)l * M_ * 1024 + dir * 512;
            hw_step_kernel<<<256, 512, 0, stream>>>(Hh, W1, bias + 1024, oF, 1024, nullptr);
        }
    }
}

// Round 4
// 812.137 us; speedup vs baseline: 1.3649x; 1.3649x over previous
//
#include <hip/hip_runtime.h>
#include <hip/hip_bf16.h>

#define B_ 16
#define S_ 2048
#define D_ 512
#define M_ (B_ * S_)  // 32768 rows for the GEMMs

typedef __attribute__((ext_vector_type(8))) _Float16 f16x8;
typedef __attribute__((ext_vector_type(4))) float f32x4;

// Async global->LDS direct copy, 16B per lane. LDS dest must be
// wave-uniform base + lane*16 (our staging layouts satisfy this: tid*16B).
#define GLOAD_LDS16(gp, lp)                                                   \
    __builtin_amdgcn_global_load_lds(                                         \
        (const __attribute__((address_space(1))) unsigned int*)(gp),          \
        (__attribute__((address_space(3))) unsigned int*)(lp), 16, 0, 0)

// ---------------------------------------------------------------------------
// Weight prep: cast fp32 W[l][h][512][1024] -> fp16 Wt[mat][1024][512]
// (transposed so B-operand fragments are contiguous 16B runs in k).
// 32x32 LDS transpose tiles, both global sides coalesced (R3).
// fp16 (not bf16): bf16 GEMM rounding amplified via sigmoid-gate * large-x
// gave absmax 4.5 > 1.68 (R1); fp16 cuts input rounding 8x -> 0.64 (R2).
// ---------------------------------------------------------------------------
__global__ __launch_bounds__(256) void prep_w_kernel(
    const float* __restrict__ fwW, const float* __restrict__ bwW,
    _Float16* __restrict__ Wt)
{
    __shared__ float tile[32][33];
    int bid = blockIdx.x;            // 8 mats * 16 k-tiles * 32 n-tiles = 4096
    int mat = bid >> 9;
    int t   = bid & 511;
    int kt  = t >> 5;                // 0..15  (k-tile)
    int nt  = t & 31;                // 0..31  (n-tile)
    int l   = mat >> 2;
    int dir = (mat >> 1) & 1;
    int h   = mat & 1;
    const float* src = (dir ? bwW : fwW) + (long long)(l * 2 + h) * (512LL * 1024);

    int tx = threadIdx.x & 31;       // fast dim (coalesced)
    int ty = threadIdx.x >> 5;       // 0..7
#pragma unroll
    for (int j = 0; j < 4; ++j) {
        int k = kt * 32 + ty + j * 8;
        tile[ty + j * 8][tx] = src[(long long)k * 1024 + nt * 32 + tx];
    }
    __syncthreads();
    _Float16* dst = Wt + (long long)mat * (1024LL * 512);
#pragma unroll
    for (int j = 0; j < 4; ++j) {
        int n = nt * 32 + ty + j * 8;
        dst[(long long)n * 512 + kt * 32 + tx] = (_Float16)tile[tx][ty + j * 8];
    }
}

// ---------------------------------------------------------------------------
// Band conv along S. R6: handles BOTH directions in one dispatch
// (dir = blockIdx.y). causal iff (dir==0 && causal0). Weights: wf for dir 0,
// wb for dir 1. src offset dir*dir_off; Th offset dir*Th_ds.
// ---------------------------------------------------------------------------
__global__ __launch_bounds__(256) void band_conv_kernel(
    const float* __restrict__ src, long long bstride, int rstride,
    long long dir_off,
    const float* __restrict__ wf, const float* __restrict__ wb, int causal0,
    _Float16* __restrict__ Th, long long Th_ds)
{
    int dir = blockIdx.y;
    int causal = (dir == 0) ? causal0 : 0;
    const float* w17 = dir ? wb : wf;
    src += (long long)dir * dir_off;
    Th  += (long long)dir * Th_ds;

    int id = blockIdx.x * 256 + threadIdx.x;  // B * (S/4) * D threads
    int c  = id & (D_ - 1);
    int tt = (id >> 9) & (S_ / 4 - 1);
    int b  = id >> 18;
    int t0 = tt * 4;

    float w[17];
#pragma unroll
    for (int e = 0; e < 17; ++e) w[e] = w17[e];

    float buf[20];
    int tbase = t0 - (causal ? 16 : 0);
    const float* sp = src + (long long)b * bstride + c;
#pragma unroll
    for (int i = 0; i < 20; ++i) {
        int t = tbase + i;
        buf[i] = (t >= 0 && t < S_) ? sp[(long long)t * rstride] : 0.f;
    }
#pragma unroll
    for (int j = 0; j < 4; ++j) {
        float a = 0.f;
#pragma unroll
        for (int e = 0; e <= 16; ++e) a = fmaf(w[e], buf[j + e], a);
        Th[((long long)(b * S_ + t0 + j)) * D_ + c] = (_Float16)a;
    }
}

// ---------------------------------------------------------------------------
// One highway iteration, fused: proj = X(fp16) @ W(fp16) + b, then
// out = sigmoid(gate)*x + (1-sigmoid(gate))*relu(nonlinear).
//
// R6: phase code reverted to the R4-measured-best version EXACTLY (R5's
// extra sched_barrier(0) pins were the m141 failure mode; its mid-loop
// epilogue put ~128 VMEM ops between barriers so every vmcnt(2) drained
// epilogue stores -> 821->1108 regression). New in R6: dir = blockIdx.y
// merges the fw/bw GEMMs into one dispatch (fewer stream drains; makes
// hw_step visible in rocprof top-5 for the next diagnosis round).
//
// Geometry: BM=256 rows x 128 out cols (256 proj cols: nonlinear + gate),
// BK=64, 8 K-tiles (K=512), 512 threads = 8 waves (4 M-waves x 2 N-waves).
// LDS 128KB: A[2buf][256][64] fp16 + B[2buf][256][64] fp16 (B local rows
// 0-127 = nonlinear cols, 128-255 = gate cols). 1 block/CU.
//
// Per K-tile: 4 phases = (h = p&1: B-half) x (ks = p>>1: k-half).
// Phase: {ds_read frags; stage one half-tile; [p3: s_waitcnt vmcnt(2)];
//         s_barrier; lgkmcnt(0); setprio(1); 16 MFMA; setprio(0); s_barrier}.
// Stage schedule (race-analyzed against last-use phases):
//   p0: Alo(kt+1)->buf^1, p1: Ahi(kt+1)->buf^1, p2: Bhi(kt+1)->buf^1,
//   p3: Blo(kt+2)->buf (Blo(kt) dead after p2; trailing barrier orders).
// vmcnt(2) at p3 => kt+1's halves landed; Blo(kt+2) stays in flight ACROSS
// barriers (T4: never drain to 0 in the main loop; kt==6 drains as
// pipeline epilogue).
//
// MFMA 16x16x32 f16; verified layouts (dtype-independent on gfx950):
//   A frag: A[m=lane&15][k=q*8+j]; B frag: B[k=q*8+j][n=lane&15]
//   C/D:    row(m)=q*4+reg, col(n)=lane&15
// T2 swizzle: LDS byte = row*128 + (colbyte ^ ((row&7)<<4)); pre-permuted
// global source keeps the global_load_lds dest linear (rule 21).
// K-accumulation order identical to R3/R4 -> absmax stays 0.71875.
// ---------------------------------------------------------------------------
__global__ __launch_bounds__(512, 2) void hw_step_kernel(
    const _Float16* __restrict__ Xh, long long Xh_ds,   // [M][512] per dir
    const _Float16* __restrict__ Wt, long long Wt_ds,   // [1024][512] per dir
    const float* __restrict__ bias0,                    // [1024] dir 0
    const float* __restrict__ bias1,                    // [1024] dir 1
    float* __restrict__ outF, int outF_stride, long long outF_ds,  // may be null
    _Float16* __restrict__ outH, long long outH_ds)                // may be null
{
    __shared__ _Float16 lds[65536];   // 128KB: A at byte 0, B at byte 65536
    char* ldsb = (char*)lds;

    int tid = threadIdx.x;

    // Per-direction operand selection (R6).
    int dir = blockIdx.y;
    Xh += (long long)dir * Xh_ds;
    Wt += (long long)dir * Wt_ds;
    const float* bias = dir ? bias1 : bias0;
    if (outF) outF += (long long)dir * outF_ds;
    if (outH) outH += (long long)dir * outH_ds;

    // XCD-chunked swizzle: x-grid 512, 64/XCD, col-block fastest within the
    // chunk -> 4 col-blocks sharing an A row-panel co-reside on one XCD L2.
    int f = blockIdx.x;
    int L = (f & 7) * 64 + (f >> 3);
    int colb = L & 3;                 // 0..3
    int rowb = L >> 2;                // 0..127
    long long m0 = (long long)rowb * 256;
    int n0 = colb * 128;              // output-column base (0..511 space)

    int lane = tid & 63;
    int wave = tid >> 6;
    int wave_m = wave >> 1;           // 0..3 -> 64 rows each
    int wave_n = wave & 1;            // 0..1 -> 64 out cols each
    int wrow = wave_m * 64;
    int wn   = wave_n * 64;
    int ln = lane & 15;
    int q  = lane >> 4;

    // staging constants: thread t stages LDS slot (j*512+t)*16 of a 16KB
    // half-tile (128 rows x 128B). Local row = j*64 + (t>>3); source column
    // pre-permuted so the linear LDS write realizes the XOR-swizzle:
    // col_fp16 = kt*64 + 8*((t&7) ^ (row&7)).
    int rloc  = tid >> 3;                         // 0..63
    int cperm = 8 * ((tid & 7) ^ (rloc & 7));     // fp16 units, 16B-aligned
    const _Float16* gA  = Xh + (m0 + rloc) * 512 + cperm;
    const _Float16* gBn = Wt + (long long)(n0 + rloc) * 512 + cperm;
    const _Float16* gBg = Wt + (long long)(512 + n0 + rloc) * 512 + cperm;

    // half-tile stage: b=buffer, kt=K-tile, h2=half (A: row-half, B: nl/gate)
    auto stageA = [&](int b, int kt, int h2) {
#pragma unroll
        for (int j = 0; j < 2; ++j)
            GLOAD_LDS16(gA + (long long)(h2 * 128 + j * 64) * 512 + kt * 64,
                        ldsb + b * 32768 + h2 * 16384 + (j * 512 + tid) * 16);
    };
    auto stageB = [&](int b, int kt, int h2) {
        const _Float16* g = h2 ? gBg : gBn;
#pragma unroll
        for (int j = 0; j < 2; ++j)
            GLOAD_LDS16(g + (long long)(j * 64) * 512 + kt * 64,
                        ldsb + 65536 + b * 32768 + h2 * 16384 + (j * 512 + tid) * 16);
    };

    f32x4 acc[2][4][4];   // [h][jn][i]
#pragma unroll
    for (int h = 0; h < 2; ++h)
#pragma unroll
        for (int jn = 0; jn < 4; ++jn)
#pragma unroll
            for (int i = 0; i < 4; ++i) acc[h][jn][i] = (f32x4){0.f, 0.f, 0.f, 0.f};

    // ---- prologue: K-tile0 complete + Blo(1); vmcnt(2) leaves Blo(1) in flight
    stageB(0, 0, 0);
    stageA(0, 0, 0);
    stageA(0, 0, 1);
    stageB(0, 0, 1);
    stageB(1, 1, 0);
    asm volatile("s_waitcnt vmcnt(2)" ::: "memory");
    __builtin_amdgcn_s_barrier();

    f16x8 af[4];
    for (int kt = 0; kt < 8; ++kt) {
        int b = kt & 1;
        const char* Ab = ldsb + b * 32768;
        const char* Bb = ldsb + 65536 + b * 32768;
#pragma unroll
        for (int p = 0; p < 4; ++p) {
            const int h = p & 1, ks = p >> 1;
            const int cb = ks * 64 + q * 16;   // colbyte before swizzle
            // ds_read register subtiles (A reused across the two h-phases)
            if ((p & 1) == 0) {
#pragma unroll
                for (int i = 0; i < 4; ++i) {
                    int row = wrow + i * 16 + ln;
                    af[i] = *(const f16x8*)(Ab + row * 128 + (cb ^ ((row & 7) << 4)));
                }
            }
            f16x8 bf[4];
#pragma unroll
            for (int jn = 0; jn < 4; ++jn) {
                int row = h * 128 + wn + jn * 16 + ln;
                bf[jn] = *(const f16x8*)(Bb + row * 128 + (cb ^ ((row & 7) << 4)));
            }
            // stage (counted-vmcnt pipeline; see schedule above)
            if (p == 0) { if (kt + 1 < 8) stageA(b ^ 1, kt + 1, 0); }
            if (p == 1) { if (kt + 1 < 8) stageA(b ^ 1, kt + 1, 1); }
            if (p == 2) { if (kt + 1 < 8) stageB(b ^ 1, kt + 1, 1); }
            if (p == 3) {
                if (kt + 2 < 8) stageB(b, kt + 2, 0);
                if (kt < 6)       asm volatile("s_waitcnt vmcnt(2)" ::: "memory");
                else if (kt == 6) asm volatile("s_waitcnt vmcnt(0)" ::: "memory");
            }
            __builtin_amdgcn_s_barrier();
            asm volatile("s_waitcnt lgkmcnt(0)" ::: "memory");
            __builtin_amdgcn_sched_barrier(0);
            __builtin_amdgcn_s_setprio(1);
#pragma unroll
            for (int jn = 0; jn < 4; ++jn)
#pragma unroll
                for (int i = 0; i < 4; ++i)
                    acc[h][jn][i] = __builtin_amdgcn_mfma_f32_16x16x32_f16(
                        af[i], bf[jn], acc[h][jn][i], 0, 0, 0);
            __builtin_amdgcn_s_setprio(0);
            __builtin_amdgcn_s_barrier();
        }
    }

    // ---- Epilogue: restage x-tile Xh[m0..+256)[n0..+128) (64KB fp16) into
    // the A region with 8 coalesced global_load_lds (source is L2-hot: it is
    // a column-slice of the A panel this XCD just streamed). Linear layout
    // [256][128] fp16; minor read conflicts are negligible vs the K-loop.
#pragma unroll
    for (int j = 0; j < 8; ++j) {
        int idx = j * 512 + tid;
        int row = idx >> 4;               // 0..255
        int col = (idx & 15) * 8;         // fp16 col 0..120
        GLOAD_LDS16(Xh + (m0 + row) * 512 + n0 + col, ldsb + idx * 16);
    }
    asm volatile("s_waitcnt vmcnt(0)" ::: "memory");
    __builtin_amdgcn_s_barrier();

#pragma unroll
    for (int jn = 0; jn < 4; ++jn) {
        int oc = wn + jn * 16 + ln;       // 0..127 local out col
        int c  = n0 + oc;                 // 0..511
        float bnl = bias[c];
        float bg  = bias[512 + c];
#pragma unroll
        for (int i = 0; i < 4; ++i) {
#pragma unroll
            for (int r = 0; r < 4; ++r) {
                int xr = wrow + i * 16 + q * 4 + r;
                long long m = m0 + xr;
                float nl = acc[0][jn][i][r] + bnl;
                float gt = acc[1][jn][i][r] + bg;
                float g  = 1.f / (1.f + __expf(-gt));
                float xv = (float)lds[xr * 128 + oc];
                float o  = g * xv + (1.f - g) * fmaxf(nl, 0.f);
                if (outF) outF[m * (long long)outF_stride + c] = o;
                if (outH) outH[m * 512 + c] = (_Float16)o;
            }
        }
    }
}

// ---------------------------------------------------------------------------
extern "C" void kernel_launch(void* const* d_in, const int* in_sizes, int n_in,
                              void* d_out, int out_size, void* d_ws, size_t ws_size,
                              hipStream_t stream)
{
    const float* inputs  = (const float*)d_in[0];
    // d_in[1] = masks: all ones, unused by the reference
    const float* fw_band = (const float*)d_in[2];
    const float* bw_band = (const float*)d_in[3];
    const float* fw_W    = (const float*)d_in[4];
    const float* fw_b    = (const float*)d_in[5];
    const float* bw_W    = (const float*)d_in[6];
    const float* bw_b    = (const float*)d_in[7];
    float* out = (float*)d_out;  // [2][16][2048][1024]

    char* ws = (char*)d_ws;
    const size_t SZ_TH  = (size_t)M_ * D_ * 2;        // 32 MB fp16 activation
    const size_t SZ_WT  = (size_t)8 * 1024 * 512 * 2; // 8 MB fp16 weights
    const long long MATSZ = 1024LL * 512;             // elements per weight mat
    const int band_grid = (B_ * (S_ / 4) * D_) / 256;

    if (ws_size >= 4 * SZ_TH + SZ_WT) {
        // ---- merged path: per-dir Th/Hh buffers, dir = blockIdx.y ----
        _Float16* Th2 = (_Float16*)(ws);
        _Float16* Hh2 = (_Float16*)(ws + 2 * SZ_TH);
        _Float16* Wt  = (_Float16*)(ws + 4 * SZ_TH);
        prep_w_kernel<<<4096, 256, 0, stream>>>(fw_W, bw_W, Wt);

        for (int l = 0; l < 2; ++l) {
            const float* src; long long bstride; int rstride; long long doff;
            if (l == 0) { src = inputs; bstride = (long long)S_ * D_; rstride = D_; doff = 0; }
            else {
                src = out + (long long)(l - 1) * M_ * 1024;
                bstride = (long long)S_ * 1024; rstride = 1024; doff = 512;
            }
            band_conv_kernel<<<dim3(band_grid, 2), 256, 0, stream>>>(
                src, bstride, rstride, doff,
                fw_band + l * 17, bw_band + l * 17, 1,
                Th2, (long long)M_ * D_);

            // highway iter 0: Th2 -> Hh2   (W mats 4l / 4l+2, dir stride 2 mats)
            hw_step_kernel<<<dim3(512, 2), 512, 0, stream>>>(
                Th2, (long long)M_ * 512,
                Wt + (size_t)(4 * l) * MATSZ, 2 * MATSZ,
                fw_b + l * 2048, bw_b + l * 2048,
                nullptr, 0, 0, Hh2, (long long)M_ * 512);
            // highway iter 1: Hh2 -> out slice (fp32, stride 1024, dir off 512)
            hw_step_kernel<<<dim3(512, 2), 512, 0, stream>>>(
                Hh2, (long long)M_ * 512,
                Wt + (size_t)(4 * l + 1) * MATSZ, 2 * MATSZ,
                fw_b + l * 2048 + 1024, bw_b + l * 2048 + 1024,
                out + (long long)l * M_ * 1024, 1024, 512, nullptr, 0);
        }
    } else {
        // ---- fallback: serial per-(l,dir) chains in the 72 MB layout ----
        _Float16* Th = (_Float16*)(ws);
        _Float16* Hh = (_Float16*)(ws + SZ_TH);
        _Float16* Wt = (_Float16*)(ws + 2 * SZ_TH);
        prep_w_kernel<<<4096, 256, 0, stream>>>(fw_W, bw_W, Wt);

        for (int l = 0; l < 2; ++l) {
            for (int dir = 0; dir < 2; ++dir) {
                const float* src; long long bstride; int rstride;
                if (l == 0) { src = inputs; bstride = (long long)S_ * D_; rstride = D_; }
                else {
                    src = out + (long long)(l - 1) * M_ * 1024 + dir * 512;
                    bstride = (long long)S_ * 1024; rstride = 1024;
                }
                const float* band = (dir ? bw_band : fw_band) + l * 17;
                band_conv_kernel<<<dim3(band_grid, 1), 256, 0, stream>>>(
                    src, bstride, rstride, 0, band, band, dir == 0 ? 1 : 0, Th, 0);

                const _Float16* W0 = Wt + (size_t)((l * 2 + dir) * 2 + 0) * MATSZ;
                const _Float16* W1 = Wt + (size_t)((l * 2 + dir) * 2 + 1) * MATSZ;
                const float* bias = (dir ? bw_b : fw_b) + (size_t)(l * 2) * 1024;

                hw_step_kernel<<<dim3(512, 1), 512, 0, stream>>>(
                    Th, 0, W0, 0, bias, bias, nullptr, 0, 0, Hh, 0);
                float* oF = out + (long long)l * M_ * 1024 + dir * 512;
                hw_step_kernel<<<dim3(512, 1), 512, 0, stream>>>(
                    Hh, 0, W1, 0, bias + 1024, bias + 1024, oF, 1024, 0, nullptr, 0);
            }
        }
    }
}